// Round 6
// baseline (4974.247 us; speedup 1.0000x reference)
//
#include <hip/hip_runtime.h>
#include <hip/hip_bf16.h>

// SenseMemAct: sense Linear -> nBRC scan (L=1024) -> actor Linear -> softmax
// f32 in / f32 out. R5: 4.26ms. H staging was 4096 agent-scope 8B atomic
// loads/WG/step (uncoalesced MALL storm). R6: 16-slot hbuf ring -> plain
// coalesced b128 H loads (L2-cacheable; freshness by per-step-unique
// addresses + agent acquire fence every 16 steps). Publishes stay
// write-through atomic; out stores become atomic (inv-safe).

#define B_TOT 64
#define L_SEQ 1024
#define N_IN 64
#define INSZ 128
#define MEM 1024
#define DEC 3

#define NGROUP 4
#define BG 16
#define NMEM 64
#define RING 16

typedef __hip_bfloat16 bf16;
typedef short bf16x8 __attribute__((ext_vector_type(8)));
typedef float f32x4 __attribute__((ext_vector_type(4)));
typedef unsigned long long ull;

// ---- workspace layout (bytes) ----
#define OFF_INPUTS 0
#define SZ_INPUTS  (L_SEQ * 64 * INSZ * 2)                 // 16 MB (bf16)
#define OFF_WMM    (OFF_INPUTS + SZ_INPUTS)
#define SZ_WMM     (128 * 32 * 64 * 8 * 2)                 // 4 MB
#define OFF_WIM    (OFF_WMM + SZ_WMM)
#define SZ_WIM     (192 * 4 * 64 * 8 * 2)                  // 0.75 MB
#define OFF_HBUF   (OFF_WIM + SZ_WIM)
#define SZ_HBUF    (RING * NGROUP * BG * MEM * 2)          // 2 MB
#define OFF_CTR    (OFF_HBUF + SZ_HBUF)
#define SZ_CTR     (NGROUP * 64 * 4)                       // arrival slots

__device__ __forceinline__ float fast_tanh(float x) {
    float e = __expf(2.f * x);
    return 1.f - 2.f / (e + 1.f);
}
__device__ __forceinline__ float fast_sigmoid(float x) {
    return 1.f / (1.f + __expf(-x));
}

// ---------------- sense: inputs = x @ W_sense + b_sense ----------------
__global__ void k_sense(const float* __restrict__ x, const float* __restrict__ Ws,
                        const float* __restrict__ bs, bf16* __restrict__ inputs) {
    int t = blockIdx.x;
    int tid = threadIdx.x;
    __shared__ float xls[64][64];
    __shared__ float wls[64][128];
    for (int idx = tid; idx < 64 * 64; idx += 256) {
        int b = idx >> 6, k = idx & 63;
        xls[b][k] = x[((size_t)b * L_SEQ + t) * N_IN + k];
    }
    for (int idx = tid; idx < 64 * 128; idx += 256) {
        int k = idx >> 7, j = idx & 127;
        wls[k][j] = Ws[k * INSZ + j];
    }
    __syncthreads();
    int j = tid & 127;
    int bh = tid >> 7;
    float bj = bs[j];
    for (int bi = 0; bi < 32; ++bi) {
        int b = bh * 32 + bi;
        float acc = bj;
#pragma unroll
        for (int k = 0; k < 64; ++k) acc += xls[b][k] * wls[k][j];
        inputs[((size_t)t * 64 + b) * INSZ + j] = (bf16)acc;
    }
}

// ---------------- pack weights into bf16 MFMA B-fragment order ----------------
// frag element (ct, kb, lane, j): n = ct*16 + (lane&15); k = kb*32 + (lane>>4)*8 + j
__global__ void k_pack(const float* __restrict__ Wmm, const float* __restrict__ Wim,
                       bf16* __restrict__ pmm, bf16* __restrict__ pim) {
    int idx = blockIdx.x * 256 + threadIdx.x;
    const int NMMF = 128 * 32 * 64 * 8;  // 2097152
    if (idx < NMMF) {
        int j = idx & 7, lane = (idx >> 3) & 63, kb = (idx >> 9) & 31, ct = idx >> 14;
        int n = ct * 16 + (lane & 15);
        int k = kb * 32 + ((lane >> 4) << 3) + j;
        pmm[idx] = (bf16)Wmm[(size_t)k * 2048 + n];
    } else {
        int idx2 = idx - NMMF;
        if (idx2 < 192 * 4 * 64 * 8) {
            int j = idx2 & 7, lane = (idx2 >> 3) & 63, kb = (idx2 >> 9) & 3, ct = idx2 >> 11;
            int n = ct * 16 + (lane & 15);
            int k = kb * 32 + ((lane >> 4) << 3) + j;
            pim[idx2] = (bf16)Wim[(size_t)k * 3072 + n];
        }
    }
}

// ---------------- persistent recurrent kernel ----------------
__launch_bounds__(256, 1)
__global__ void k_main(const bf16* __restrict__ inputs, const bf16* __restrict__ pmm,
                       const bf16* __restrict__ pim, const float* __restrict__ Wact,
                       const float* __restrict__ bact, bf16* __restrict__ hbuf,
                       float* __restrict__ out, unsigned int* __restrict__ ctr) {
    const int g = blockIdx.x & 3;       // group (16 batches); spans 2 XCDs under %8 rr
    const int m = blockIdx.x >> 2;      // member (16 h-cols)
    const int tid = (int)threadIdx.x;
    const int wave = tid >> 6;
    const int lane = tid & 63;
    const int r16 = lane & 15;          // A-row / B-col within tile
    const int q = lane >> 4;            // quad
    const int cl = tid & 15;            // elementwise local col
    const int bloc = tid >> 4;          // elementwise local batch

    __shared__ bf16 Hlds[16][1032];     // stride 1032 elems (16B-aligned, odd x16)
    __shared__ float ilds[2][3][16][16];
    __shared__ float mlds[4][16][16];
    __shared__ float ownh[16][16];
    __shared__ bf16 hstage[16][16];
    __shared__ float wact_lds[1024 * 3];
    __shared__ float aplds[4][3];
    __shared__ float bactl[3];

    for (int idx = tid; idx < 1024 * 3; idx += 256) wact_lds[idx] = Wact[idx];
    if (tid < 3) bactl[tid] = bact[tid];

    // register-resident W_mm fragments: waves 0,1 -> ct=m (m_a); waves 2,3 -> ct=64+m (m_c)
    bf16x8 wb[16];
    {
        int ct = (wave < 2) ? m : 64 + m;
        int kh = wave & 1;
#pragma unroll
        for (int i = 0; i < 16; ++i) {
            int kb = kh * 16 + i;
            wb[i] = *(const bf16x8*)(pmm + (((size_t)ct * 32 + kb) * 64 + lane) * 8);
        }
    }
    // W_im fragments: wave w in {0,1,2} handles i_a / i_c / i_o  (ct2 = w*64 + m)
    bf16x8 wi[4];
    if (wave < 3) {
        int ct2 = wave * 64 + m;
#pragma unroll
        for (int kb2 = 0; kb2 < 4; ++kb2)
            wi[kb2] = *(const bf16x8*)(pim + (((size_t)ct2 * 4 + kb2) * 64 + lane) * 8);
    }
    ownh[bloc][cl] = 0.f;

    auto comp_iacc = [&](int t) -> f32x4 {
        f32x4 a = {0.f, 0.f, 0.f, 0.f};
        if (wave < 3) {
#pragma unroll
            for (int kb2 = 0; kb2 < 4; ++kb2) {
                bf16x8 af = *(const bf16x8*)(inputs +
                    ((size_t)t * 64 + g * 16 + r16) * INSZ + kb2 * 32 + q * 8);
                a = __builtin_amdgcn_mfma_f32_16x16x32_bf16(af, wi[kb2], a, 0, 0, 0);
            }
        }
        return a;
    };

    // actor partial: thread covers 4 cols of Hlds[hrow]; wave-reduce; leaders -> aplds
    auto actor_emit = [&](int hrow) {
        float p0 = 0.f, p1 = 0.f, p2 = 0.f;
        int c0 = tid * 4;
        const bf16* hp = &Hlds[hrow][c0];
#pragma unroll
        for (int i = 0; i < 4; ++i) {
            float hv = (float)hp[i];
            p0 += hv * wact_lds[(c0 + i) * 3 + 0];
            p1 += hv * wact_lds[(c0 + i) * 3 + 1];
            p2 += hv * wact_lds[(c0 + i) * 3 + 2];
        }
#pragma unroll
        for (int off = 32; off >= 1; off >>= 1) {
            p0 += __shfl_xor(p0, off);
            p1 += __shfl_xor(p1, off);
            p2 += __shfl_xor(p2, off);
        }
        if (lane == 0) { aplds[wave][0] = p0; aplds[wave][1] = p1; aplds[wave][2] = p2; }
    };
    auto actor_fin = [&](int tout) {   // tid==0 only; after a barrier following emit
        float l0 = aplds[0][0] + aplds[1][0] + aplds[2][0] + aplds[3][0] + bactl[0];
        float l1 = aplds[0][1] + aplds[1][1] + aplds[2][1] + aplds[3][1] + bactl[1];
        float l2 = aplds[0][2] + aplds[1][2] + aplds[2][2] + aplds[3][2] + bactl[2];
        float mx = fmaxf(l0, fmaxf(l1, l2));
        float e0 = __expf(l0 - mx), e1 = __expf(l1 - mx), e2 = __expf(l2 - mx);
        float inv = 1.f / (e0 + e1 + e2);
        float* o = out + ((size_t)(g * 16 + m) * L_SEQ + tout) * 3;
        // atomic stores: write-through, safe vs the periodic L2 invalidate
        __hip_atomic_store(o + 0, e0 * inv, __ATOMIC_RELAXED, __HIP_MEMORY_SCOPE_AGENT);
        __hip_atomic_store(o + 1, e1 * inv, __ATOMIC_RELAXED, __HIP_MEMORY_SCOPE_AGENT);
        __hip_atomic_store(o + 2, e2 * inv, __ATOMIC_RELAXED, __HIP_MEMORY_SCOPE_AGENT);
    };

    f32x4 iacc = comp_iacc(0);
    unsigned int* slots = ctr + g * 64;   // per-WG arrival slots
    int spin_budget = 1 << 22;            // wrong-answer instead of hang on bug

#pragma clang loop unroll(disable)
    for (int t = 0; t < L_SEQ; ++t) {
        // every RING steps: drop L1/L2 so ring-slot reuse can't serve stale lines
        if (t != 0 && (t & (RING - 1)) == 0)
            __builtin_amdgcn_fence(__ATOMIC_ACQUIRE, "agent");

        // deposit this step's input-projection tiles
        if (wave < 3) {
#pragma unroll
            for (int reg = 0; reg < 4; ++reg)
                ilds[t & 1][wave][q * 4 + reg][r16] = iacc[reg];
        }
        // stage H^{t-1} from ring slot (t-1)&15: PLAIN coalesced b128 loads.
        // Fresh by construction: slot addresses unique within a 16-step window,
        // all fills happen after this step's flags (post MALL-ack'd publish).
        {
            const bf16* src = hbuf +
                ((size_t)(((t + RING - 1) & (RING - 1)) * NGROUP + g)) * BG * MEM;
            bf16x8 tmp[8];
#pragma unroll
            for (int it = 0; it < 8; ++it) {
                int fi = it * 256 + tid;          // 0..2047 chunks of 8 elems
                tmp[it] = *(const bf16x8*)(src + (size_t)(fi >> 7) * MEM + (fi & 127) * 8);
            }
#pragma unroll
            for (int it = 0; it < 8; ++it) {
                int fi = it * 256 + tid;
                *(bf16x8*)(&Hlds[fi >> 7][(fi & 127) * 8]) = tmp[it];
            }
        }
        __syncthreads();

        // m = H @ W_mm slice: wave owns (m_a|m_c) x K-half, 16 MFMAs, B from registers
        {
            f32x4 macc = {0.f, 0.f, 0.f, 0.f};
            int kh = wave & 1;
#pragma unroll
            for (int i = 0; i < 16; ++i) {
                int kb = kh * 16 + i;
                bf16x8 af = *(const bf16x8*)(&Hlds[r16][kb * 32 + q * 8]);
                macc = __builtin_amdgcn_mfma_f32_16x16x32_bf16(af, wb[i], macc, 0, 0, 0);
            }
#pragma unroll
            for (int reg = 0; reg < 4; ++reg)
                mlds[wave][q * 4 + reg][r16] = macc[reg];
        }
        // actor partials for logits[t-1] of batch g*16+m (members m<16 only)
        if (m < 16 && t > 0) actor_emit(m);
        __syncthreads();

        // elementwise nBRC update: one thread per (batch, col)
        {
            float ma = mlds[0][bloc][cl] + mlds[1][bloc][cl];
            float mc = mlds[2][bloc][cl] + mlds[3][bloc][cl];
            float ia = ilds[t & 1][0][bloc][cl];
            float ic = ilds[t & 1][1][bloc][cl];
            float io = ilds[t & 1][2][bloc][cl];
            float h0 = ownh[bloc][cl];
            float a = 1.f + fast_tanh(ia + ma);
            float c = fast_sigmoid(ic + mc);
            float hn = c * h0 + (1.f - c) * fast_tanh(io + a * h0);
            ownh[bloc][cl] = hn;
            hstage[bloc][cl] = (bf16)hn;
        }
        __syncthreads();   // hstage complete; aplds complete

        // actor finish + output store (one thread)
        if (m < 16 && t > 0 && tid == 0) actor_fin(t - 1);

        // publish H^t into ring slot t&15: wave0 8B write-through stores,
        // in-wave drain, then relaxed flag
        if (tid < 64) {
            int row = tid >> 2, chunk = tid & 3;
            ull v = *(const ull*)(&hstage[row][chunk * 4]);
            ull* dst = (ull*)(hbuf + ((size_t)((t & (RING - 1)) * NGROUP + g)) * BG * MEM +
                              (size_t)row * MEM + m * 16) + chunk;
            __hip_atomic_store(dst, v, __ATOMIC_RELAXED, __HIP_MEMORY_SCOPE_AGENT);
            asm volatile("s_waitcnt vmcnt(0)" ::: "memory");   // acked at MALL
            if (tid == 0)
                __hip_atomic_store(&slots[m], (unsigned)(t + 1), __ATOMIC_RELAXED,
                                   __HIP_MEMORY_SCOPE_AGENT);
        }

        // waves 0-2 prefetch next i-proj while wave 3 polls all 64 slots
        if (t + 1 < L_SEQ) iacc = comp_iacc(t + 1);
        if (wave == 3) {
            bool done = false;
            while (!done && --spin_budget > 0) {
                unsigned v = __hip_atomic_load(&slots[lane], __ATOMIC_RELAXED,
                                               __HIP_MEMORY_SCOPE_AGENT);
                done = (bool)__all((int)(v >= (unsigned)(t + 1)));
            }
        }
        __syncthreads();
    }

    // epilogue: logits/softmax for t = L-1 from ring slot 1023&15 = 15.
    // Slot 15 was last read at step 1008 -> must invalidate before re-reading.
    if (m < 16) {
        __builtin_amdgcn_fence(__ATOMIC_ACQUIRE, "agent");
        const bf16* src = hbuf + ((size_t)(((L_SEQ - 1) & (RING - 1)) * NGROUP + g)) * BG * MEM +
                          (size_t)m * MEM;
        *(ull*)(&Hlds[0][tid * 4]) = *(const ull*)(src + tid * 4);
        __syncthreads();
        actor_emit(0);
        __syncthreads();
        if (tid == 0) actor_fin(L_SEQ - 1);
    }
}

extern "C" void kernel_launch(void* const* d_in, const int* in_sizes, int n_in,
                              void* d_out, int out_size, void* d_ws, size_t ws_size,
                              hipStream_t stream) {
    const float* x    = (const float*)d_in[0];
    const float* Ws   = (const float*)d_in[1];
    const float* bs   = (const float*)d_in[2];
    const float* Wim  = (const float*)d_in[3];
    const float* Wmm  = (const float*)d_in[4];
    const float* Wact = (const float*)d_in[5];
    const float* bact = (const float*)d_in[6];

    char* ws = (char*)d_ws;
    bf16* inputs = (bf16*)(ws + OFF_INPUTS);
    bf16* pmm    = (bf16*)(ws + OFF_WMM);
    bf16* pim    = (bf16*)(ws + OFF_WIM);
    bf16* hbuf   = (bf16*)(ws + OFF_HBUF);
    unsigned int* ctr = (unsigned int*)(ws + OFF_CTR);

    hipMemsetAsync(hbuf, 0, SZ_HBUF, stream);   // slot 15 zeros = H^{-1}
    hipMemsetAsync(ctr, 0, SZ_CTR, stream);

    k_sense<<<L_SEQ, 256, 0, stream>>>(x, Ws, bs, inputs);
    k_pack<<<(128 * 32 * 64 * 8 + 192 * 4 * 64 * 8) / 256, 256, 0, stream>>>(Wmm, Wim, pmm, pim);
    k_main<<<NGROUP * NMEM, 256, 0, stream>>>(inputs, pmm, pim, Wact, bact, hbuf,
                                              (float*)d_out, ctr);
}

// Round 7
// 4324.076 us; speedup vs baseline: 1.1504x; 1.1504x over previous
//
#include <hip/hip_runtime.h>
#include <hip/hip_bf16.h>

// SenseMemAct: sense Linear -> nBRC scan (L=1024) -> actor Linear -> softmax
// f32 in / f32 out. R6: 4.97ms — H-broadcast MALL amplification (members x
// 32KB/step) is the floor, not the sync RTTs. R7: 32 members x 32 cols
// (grid 128): halves MALL read traffic, halves flag fan-in; wb[32]
// register-resident (128 VGPR); ring + plain b128 staging kept.

#define B_TOT 64
#define L_SEQ 1024
#define N_IN 64
#define INSZ 128
#define MEM 1024
#define DEC 3

#define NGROUP 4
#define BG 16
#define NMEM 32
#define RING 16

typedef __hip_bfloat16 bf16;
typedef short bf16x8 __attribute__((ext_vector_type(8)));
typedef float f32x4 __attribute__((ext_vector_type(4)));
typedef unsigned long long ull;

// ---- workspace layout (bytes) ----
#define OFF_INPUTS 0
#define SZ_INPUTS  (L_SEQ * 64 * INSZ * 2)                 // 16 MB (bf16)
#define OFF_WMM    (OFF_INPUTS + SZ_INPUTS)
#define SZ_WMM     (128 * 32 * 64 * 8 * 2)                 // 4 MB
#define OFF_WIM    (OFF_WMM + SZ_WMM)
#define SZ_WIM     (192 * 4 * 64 * 8 * 2)                  // 0.75 MB
#define OFF_HBUF   (OFF_WIM + SZ_WIM)
#define SZ_HBUF    (RING * NGROUP * BG * MEM * 2)          // 2 MB
#define OFF_CTR    (OFF_HBUF + SZ_HBUF)
#define SZ_CTR     (NGROUP * 64 * 4)

__device__ __forceinline__ float fast_tanh(float x) {
    float e = __expf(2.f * x);
    return 1.f - 2.f / (e + 1.f);
}
__device__ __forceinline__ float fast_sigmoid(float x) {
    return 1.f / (1.f + __expf(-x));
}

// ---------------- sense: inputs = x @ W_sense + b_sense ----------------
__global__ void k_sense(const float* __restrict__ x, const float* __restrict__ Ws,
                        const float* __restrict__ bs, bf16* __restrict__ inputs) {
    int t = blockIdx.x;
    int tid = threadIdx.x;
    __shared__ float xls[64][64];
    __shared__ float wls[64][128];
    for (int idx = tid; idx < 64 * 64; idx += 256) {
        int b = idx >> 6, k = idx & 63;
        xls[b][k] = x[((size_t)b * L_SEQ + t) * N_IN + k];
    }
    for (int idx = tid; idx < 64 * 128; idx += 256) {
        int k = idx >> 7, j = idx & 127;
        wls[k][j] = Ws[k * INSZ + j];
    }
    __syncthreads();
    int j = tid & 127;
    int bh = tid >> 7;
    float bj = bs[j];
    for (int bi = 0; bi < 32; ++bi) {
        int b = bh * 32 + bi;
        float acc = bj;
#pragma unroll
        for (int k = 0; k < 64; ++k) acc += xls[b][k] * wls[k][j];
        inputs[((size_t)t * 64 + b) * INSZ + j] = (bf16)acc;
    }
}

// ---------------- pack weights into bf16 MFMA B-fragment order ----------------
// frag element (ct, kb, lane, j): n = ct*16 + (lane&15); k = kb*32 + (lane>>4)*8 + j
__global__ void k_pack(const float* __restrict__ Wmm, const float* __restrict__ Wim,
                       bf16* __restrict__ pmm, bf16* __restrict__ pim) {
    int idx = blockIdx.x * 256 + threadIdx.x;
    const int NMMF = 128 * 32 * 64 * 8;  // 2097152
    if (idx < NMMF) {
        int j = idx & 7, lane = (idx >> 3) & 63, kb = (idx >> 9) & 31, ct = idx >> 14;
        int n = ct * 16 + (lane & 15);
        int k = kb * 32 + ((lane >> 4) << 3) + j;
        pmm[idx] = (bf16)Wmm[(size_t)k * 2048 + n];
    } else {
        int idx2 = idx - NMMF;
        if (idx2 < 192 * 4 * 64 * 8) {
            int j = idx2 & 7, lane = (idx2 >> 3) & 63, kb = (idx2 >> 9) & 3, ct = idx2 >> 11;
            int n = ct * 16 + (lane & 15);
            int k = kb * 32 + ((lane >> 4) << 3) + j;
            pim[idx2] = (bf16)Wim[(size_t)k * 3072 + n];
        }
    }
}

// ---------------- persistent recurrent kernel ----------------
__launch_bounds__(256, 1)
__global__ void k_main(const bf16* __restrict__ inputs, const bf16* __restrict__ pmm,
                       const bf16* __restrict__ pim, const float* __restrict__ Wact,
                       const float* __restrict__ bact, bf16* __restrict__ hbuf,
                       float* __restrict__ out, unsigned int* __restrict__ ctr) {
    const int g = blockIdx.x & 3;       // group (16 batches)
    const int m = blockIdx.x >> 2;      // member (32 h-cols), 0..31
    const int tid = (int)threadIdx.x;
    const int wave = tid >> 6;
    const int lane = tid & 63;
    const int r16 = lane & 15;          // A-row / B-col within tile
    const int q = lane >> 4;            // quad
    const int cl = tid & 15;            // elementwise local col (within tile)
    const int bloc = tid >> 4;          // elementwise local batch

    __shared__ bf16 Hlds[16][1032];     // stride 1032 elems (16B-aligned, odd x16)
    __shared__ float ilds[2][3][2][16][16];   // buf, gate, tile, batch, col
    __shared__ float mlds[4][16][16];         // wave tile: {a0,a1,c0,c1}
    __shared__ float ownh[16][32];
    __shared__ bf16 hstage[16][32];
    __shared__ float wact_lds[1024 * 3];
    __shared__ float aplds[4][3];
    __shared__ float bactl[3];

    for (int idx = tid; idx < 1024 * 3; idx += 256) wact_lds[idx] = Wact[idx];
    if (tid < 3) bactl[tid] = bact[tid];

    // W_mm fragments, register-resident. wave w: gate = w>>1 (0=m_a,1=m_c),
    // tile = w&1; col-tile ct = gate*64 + m*2 + tile; all 32 K-frags.
    bf16x8 wb[32];
    {
        int ct = (wave >> 1) * 64 + m * 2 + (wave & 1);
#pragma unroll
        for (int kb = 0; kb < 32; ++kb)
            wb[kb] = *(const bf16x8*)(pmm + (((size_t)ct * 32 + kb) * 64 + lane) * 8);
    }
    // W_im fragments: wave w in {0,1,2} = gate w; 2 col-tiles x 4 kb each
    bf16x8 wi[2][4];
    if (wave < 3) {
#pragma unroll
        for (int tl = 0; tl < 2; ++tl) {
            int ct2 = wave * 64 + m * 2 + tl;
#pragma unroll
            for (int kb2 = 0; kb2 < 4; ++kb2)
                wi[tl][kb2] = *(const bf16x8*)(pim + (((size_t)ct2 * 4 + kb2) * 64 + lane) * 8);
        }
    }
#pragma unroll
    for (int p = 0; p < 2; ++p) ownh[bloc][p * 16 + cl] = 0.f;

    struct I2 { f32x4 a0, a1; };
    auto comp_iacc = [&](int t) -> I2 {
        I2 r;
        r.a0 = (f32x4){0.f, 0.f, 0.f, 0.f};
        r.a1 = (f32x4){0.f, 0.f, 0.f, 0.f};
        if (wave < 3) {
#pragma unroll
            for (int kb2 = 0; kb2 < 4; ++kb2) {
                bf16x8 af = *(const bf16x8*)(inputs +
                    ((size_t)t * 64 + g * 16 + r16) * INSZ + kb2 * 32 + q * 8);
                r.a0 = __builtin_amdgcn_mfma_f32_16x16x32_bf16(af, wi[0][kb2], r.a0, 0, 0, 0);
                r.a1 = __builtin_amdgcn_mfma_f32_16x16x32_bf16(af, wi[1][kb2], r.a1, 0, 0, 0);
            }
        }
        return r;
    };

    // actor partial: thread covers 4 cols of Hlds[hrow]; wave-reduce; leaders -> aplds
    auto actor_emit = [&](int hrow) {
        float p0 = 0.f, p1 = 0.f, p2 = 0.f;
        int c0 = tid * 4;
        const bf16* hp = &Hlds[hrow][c0];
#pragma unroll
        for (int i = 0; i < 4; ++i) {
            float hv = (float)hp[i];
            p0 += hv * wact_lds[(c0 + i) * 3 + 0];
            p1 += hv * wact_lds[(c0 + i) * 3 + 1];
            p2 += hv * wact_lds[(c0 + i) * 3 + 2];
        }
#pragma unroll
        for (int off = 32; off >= 1; off >>= 1) {
            p0 += __shfl_xor(p0, off);
            p1 += __shfl_xor(p1, off);
            p2 += __shfl_xor(p2, off);
        }
        if (lane == 0) { aplds[wave][0] = p0; aplds[wave][1] = p1; aplds[wave][2] = p2; }
    };
    auto actor_fin = [&](int tout) {   // tid==0 only; after a barrier following emit
        float l0 = aplds[0][0] + aplds[1][0] + aplds[2][0] + aplds[3][0] + bactl[0];
        float l1 = aplds[0][1] + aplds[1][1] + aplds[2][1] + aplds[3][1] + bactl[1];
        float l2 = aplds[0][2] + aplds[1][2] + aplds[2][2] + aplds[3][2] + bactl[2];
        float mx = fmaxf(l0, fmaxf(l1, l2));
        float e0 = __expf(l0 - mx), e1 = __expf(l1 - mx), e2 = __expf(l2 - mx);
        float inv = 1.f / (e0 + e1 + e2);
        float* o = out + ((size_t)(g * 16 + m) * L_SEQ + tout) * 3;
        __hip_atomic_store(o + 0, e0 * inv, __ATOMIC_RELAXED, __HIP_MEMORY_SCOPE_AGENT);
        __hip_atomic_store(o + 1, e1 * inv, __ATOMIC_RELAXED, __HIP_MEMORY_SCOPE_AGENT);
        __hip_atomic_store(o + 2, e2 * inv, __ATOMIC_RELAXED, __HIP_MEMORY_SCOPE_AGENT);
    };

    I2 iacc = comp_iacc(0);
    unsigned int* slots = ctr + g * 64;   // 32 used per group
    int spin_budget = 1 << 22;

#pragma clang loop unroll(disable)
    for (int t = 0; t < L_SEQ; ++t) {
        // every RING steps: drop stale cache lines before ring-slot reuse
        if (t != 0 && (t & (RING - 1)) == 0)
            __builtin_amdgcn_fence(__ATOMIC_ACQUIRE, "agent");

        // deposit this step's input-projection tiles
        if (wave < 3) {
#pragma unroll
            for (int reg = 0; reg < 4; ++reg) {
                ilds[t & 1][wave][0][q * 4 + reg][r16] = iacc.a0[reg];
                ilds[t & 1][wave][1][q * 4 + reg][r16] = iacc.a1[reg];
            }
        }
        // stage H^{t-1} from ring slot (t-1)&15: plain coalesced b128 loads
        {
            const bf16* src = hbuf +
                ((size_t)(((t + RING - 1) & (RING - 1)) * NGROUP + g)) * BG * MEM;
            bf16x8 tmp[8];
#pragma unroll
            for (int it = 0; it < 8; ++it) {
                int fi = it * 256 + tid;
                tmp[it] = *(const bf16x8*)(src + (size_t)(fi >> 7) * MEM + (fi & 127) * 8);
            }
#pragma unroll
            for (int it = 0; it < 8; ++it) {
                int fi = it * 256 + tid;
                *(bf16x8*)(&Hlds[fi >> 7][(fi & 127) * 8]) = tmp[it];
            }
        }
        __syncthreads();

        // m = H @ W_mm: wave owns one 16x16 col-tile over K=1024 (32 MFMAs,
        // two interleaved chains for pipelining), B register-resident
        {
            f32x4 m0 = {0.f, 0.f, 0.f, 0.f};
            f32x4 m1 = {0.f, 0.f, 0.f, 0.f};
#pragma unroll
            for (int i = 0; i < 16; ++i) {
                bf16x8 a0 = *(const bf16x8*)(&Hlds[r16][(2 * i) * 32 + q * 8]);
                bf16x8 a1 = *(const bf16x8*)(&Hlds[r16][(2 * i + 1) * 32 + q * 8]);
                m0 = __builtin_amdgcn_mfma_f32_16x16x32_bf16(a0, wb[2 * i], m0, 0, 0, 0);
                m1 = __builtin_amdgcn_mfma_f32_16x16x32_bf16(a1, wb[2 * i + 1], m1, 0, 0, 0);
            }
#pragma unroll
            for (int reg = 0; reg < 4; ++reg)
                mlds[wave][q * 4 + reg][r16] = m0[reg] + m1[reg];
        }
        // actor partials for logits[t-1] of batch g*16+m (members m<16 only)
        if (m < 16 && t > 0) actor_emit(m);
        __syncthreads();

        // elementwise nBRC update: thread -> (batch bloc, cols cl and 16+cl)
        {
#pragma unroll
            for (int p = 0; p < 2; ++p) {
                float ma = mlds[p][bloc][cl];
                float mc = mlds[2 + p][bloc][cl];
                float ia = ilds[t & 1][0][p][bloc][cl];
                float ic = ilds[t & 1][1][p][bloc][cl];
                float io = ilds[t & 1][2][p][bloc][cl];
                float h0 = ownh[bloc][p * 16 + cl];
                float a = 1.f + fast_tanh(ia + ma);
                float c = fast_sigmoid(ic + mc);
                float hn = c * h0 + (1.f - c) * fast_tanh(io + a * h0);
                ownh[bloc][p * 16 + cl] = hn;
                hstage[bloc][p * 16 + cl] = (bf16)hn;
            }
        }
        __syncthreads();   // hstage complete; aplds complete

        if (m < 16 && t > 0 && tid == 0) actor_fin(t - 1);

        // publish H^t (1 KB = 128 ull): wave 0, write-through stores, drain, flag
        if (tid < 64) {
            bf16* base = hbuf + ((size_t)((t & (RING - 1)) * NGROUP + g)) * BG * MEM;
#pragma unroll
            for (int i = 0; i < 2; ++i) {
                int idx = i * 64 + lane;        // 0..127
                int row = idx >> 3, c = idx & 7;
                ull v = *(const ull*)(&hstage[row][c * 4]);
                ull* dst = (ull*)(base + (size_t)row * MEM + m * 32) + c;
                __hip_atomic_store(dst, v, __ATOMIC_RELAXED, __HIP_MEMORY_SCOPE_AGENT);
            }
            asm volatile("s_waitcnt vmcnt(0)" ::: "memory");   // acked at MALL
            if (lane == 0)
                __hip_atomic_store(&slots[m], (unsigned)(t + 1), __ATOMIC_RELAXED,
                                   __HIP_MEMORY_SCOPE_AGENT);
        }

        // waves 0-2 prefetch next i-proj while wave 3 polls the 32 slots
        if (t + 1 < L_SEQ) iacc = comp_iacc(t + 1);
        if (wave == 3) {
            bool done = false;
            while (!done && --spin_budget > 0) {
                unsigned v = __hip_atomic_load(&slots[lane & 31], __ATOMIC_RELAXED,
                                               __HIP_MEMORY_SCOPE_AGENT);
                done = (bool)__all((int)(v >= (unsigned)(t + 1)));
            }
        }
        __syncthreads();
    }

    // epilogue: logits/softmax for t = L-1 from ring slot 15 (fresh read needed)
    if (m < 16) {
        __builtin_amdgcn_fence(__ATOMIC_ACQUIRE, "agent");
        const bf16* src = hbuf + ((size_t)(((L_SEQ - 1) & (RING - 1)) * NGROUP + g)) * BG * MEM +
                          (size_t)m * MEM;
        *(ull*)(&Hlds[0][tid * 4]) = *(const ull*)(src + tid * 4);
        __syncthreads();
        actor_emit(0);
        __syncthreads();
        if (tid == 0) actor_fin(L_SEQ - 1);
    }
}

extern "C" void kernel_launch(void* const* d_in, const int* in_sizes, int n_in,
                              void* d_out, int out_size, void* d_ws, size_t ws_size,
                              hipStream_t stream) {
    const float* x    = (const float*)d_in[0];
    const float* Ws   = (const float*)d_in[1];
    const float* bs   = (const float*)d_in[2];
    const float* Wim  = (const float*)d_in[3];
    const float* Wmm  = (const float*)d_in[4];
    const float* Wact = (const float*)d_in[5];
    const float* bact = (const float*)d_in[6];

    char* ws = (char*)d_ws;
    bf16* inputs = (bf16*)(ws + OFF_INPUTS);
    bf16* pmm    = (bf16*)(ws + OFF_WMM);
    bf16* pim    = (bf16*)(ws + OFF_WIM);
    bf16* hbuf   = (bf16*)(ws + OFF_HBUF);
    unsigned int* ctr = (unsigned int*)(ws + OFF_CTR);

    hipMemsetAsync(hbuf, 0, SZ_HBUF, stream);   // slot 15 zeros = H^{-1}
    hipMemsetAsync(ctr, 0, SZ_CTR, stream);

    k_sense<<<L_SEQ, 256, 0, stream>>>(x, Ws, bs, inputs);
    k_pack<<<(128 * 32 * 64 * 8 + 192 * 4 * 64 * 8) / 256, 256, 0, stream>>>(Wmm, Wim, pmm, pim);
    k_main<<<NGROUP * NMEM, 256, 0, stream>>>(inputs, pmm, pim, Wact, bact, hbuf,
                                              (float*)d_out, ctr);
}

// Round 8
// 4215.471 us; speedup vs baseline: 1.1800x; 1.0258x over previous
//
#include <hip/hip_runtime.h>
#include <hip/hip_bf16.h>

// SenseMemAct: sense Linear -> nBRC scan (L=1024) -> actor Linear -> softmax
// f32 in / f32 out. R7: 4.32ms; member halving gave ~2% -> floor is NOT
// broadcast volume. Model: flat 64-lane atomic poll by all 128 WGs against
// 2 cache lines serializes the MALL (storm inflates every RTT).
// R8: hierarchical barrier — member-0 wave3 polls the 32 slots and writes
// one epoch[g]; everyone else polls epoch[g] with lane 0 only (+s_sleep(1)).
// ~50x fewer poll transactions for +1 RTT in the chain.

#define B_TOT 64
#define L_SEQ 1024
#define N_IN 64
#define INSZ 128
#define MEM 1024
#define DEC 3

#define NGROUP 4
#define BG 16
#define NMEM 32
#define RING 16

typedef __hip_bfloat16 bf16;
typedef short bf16x8 __attribute__((ext_vector_type(8)));
typedef float f32x4 __attribute__((ext_vector_type(4)));
typedef unsigned long long ull;

// ---- workspace layout (bytes) ----
#define OFF_INPUTS 0
#define SZ_INPUTS  (L_SEQ * 64 * INSZ * 2)                 // 16 MB (bf16)
#define OFF_WMM    (OFF_INPUTS + SZ_INPUTS)
#define SZ_WMM     (128 * 32 * 64 * 8 * 2)                 // 4 MB
#define OFF_WIM    (OFF_WMM + SZ_WMM)
#define SZ_WIM     (192 * 4 * 64 * 8 * 2)                  // 0.75 MB
#define OFF_HBUF   (OFF_WIM + SZ_WIM)
#define SZ_HBUF    (RING * NGROUP * BG * MEM * 2)          // 2 MB
#define OFF_CTR    (OFF_HBUF + SZ_HBUF)
#define SZ_CTR     (2 * NGROUP * 64 * 4)                   // slots + epoch lines

__device__ __forceinline__ float fast_tanh(float x) {
    float e = __expf(2.f * x);
    return 1.f - 2.f / (e + 1.f);
}
__device__ __forceinline__ float fast_sigmoid(float x) {
    return 1.f / (1.f + __expf(-x));
}

// ---------------- sense: inputs = x @ W_sense + b_sense ----------------
__global__ void k_sense(const float* __restrict__ x, const float* __restrict__ Ws,
                        const float* __restrict__ bs, bf16* __restrict__ inputs) {
    int t = blockIdx.x;
    int tid = threadIdx.x;
    __shared__ float xls[64][64];
    __shared__ float wls[64][128];
    for (int idx = tid; idx < 64 * 64; idx += 256) {
        int b = idx >> 6, k = idx & 63;
        xls[b][k] = x[((size_t)b * L_SEQ + t) * N_IN + k];
    }
    for (int idx = tid; idx < 64 * 128; idx += 256) {
        int k = idx >> 7, j = idx & 127;
        wls[k][j] = Ws[k * INSZ + j];
    }
    __syncthreads();
    int j = tid & 127;
    int bh = tid >> 7;
    float bj = bs[j];
    for (int bi = 0; bi < 32; ++bi) {
        int b = bh * 32 + bi;
        float acc = bj;
#pragma unroll
        for (int k = 0; k < 64; ++k) acc += xls[b][k] * wls[k][j];
        inputs[((size_t)t * 64 + b) * INSZ + j] = (bf16)acc;
    }
}

// ---------------- pack weights into bf16 MFMA B-fragment order ----------------
// frag element (ct, kb, lane, j): n = ct*16 + (lane&15); k = kb*32 + (lane>>4)*8 + j
__global__ void k_pack(const float* __restrict__ Wmm, const float* __restrict__ Wim,
                       bf16* __restrict__ pmm, bf16* __restrict__ pim) {
    int idx = blockIdx.x * 256 + threadIdx.x;
    const int NMMF = 128 * 32 * 64 * 8;  // 2097152
    if (idx < NMMF) {
        int j = idx & 7, lane = (idx >> 3) & 63, kb = (idx >> 9) & 31, ct = idx >> 14;
        int n = ct * 16 + (lane & 15);
        int k = kb * 32 + ((lane >> 4) << 3) + j;
        pmm[idx] = (bf16)Wmm[(size_t)k * 2048 + n];
    } else {
        int idx2 = idx - NMMF;
        if (idx2 < 192 * 4 * 64 * 8) {
            int j = idx2 & 7, lane = (idx2 >> 3) & 63, kb = (idx2 >> 9) & 3, ct = idx2 >> 11;
            int n = ct * 16 + (lane & 15);
            int k = kb * 32 + ((lane >> 4) << 3) + j;
            pim[idx2] = (bf16)Wim[(size_t)k * 3072 + n];
        }
    }
}

// ---------------- persistent recurrent kernel ----------------
__launch_bounds__(256, 1)
__global__ void k_main(const bf16* __restrict__ inputs, const bf16* __restrict__ pmm,
                       const bf16* __restrict__ pim, const float* __restrict__ Wact,
                       const float* __restrict__ bact, bf16* __restrict__ hbuf,
                       float* __restrict__ out, unsigned int* __restrict__ ctr) {
    const int g = blockIdx.x & 3;       // group (16 batches); WGs on 2 XCDs
    const int m = blockIdx.x >> 2;      // member (32 h-cols), 0..31
    const int tid = (int)threadIdx.x;
    const int wave = tid >> 6;
    const int lane = tid & 63;
    const int r16 = lane & 15;          // A-row / B-col within tile
    const int q = lane >> 4;            // quad
    const int cl = tid & 15;            // elementwise local col (within tile)
    const int bloc = tid >> 4;          // elementwise local batch

    __shared__ bf16 Hlds[16][1032];     // stride 1032 elems (16B-aligned, odd x16)
    __shared__ float ilds[2][3][2][16][16];   // buf, gate, tile, batch, col
    __shared__ float mlds[4][16][16];         // wave tile: {a0,a1,c0,c1}
    __shared__ float ownh[16][32];
    __shared__ bf16 hstage[16][32];
    __shared__ float wact_lds[1024 * 3];
    __shared__ float aplds[4][3];
    __shared__ float bactl[3];

    for (int idx = tid; idx < 1024 * 3; idx += 256) wact_lds[idx] = Wact[idx];
    if (tid < 3) bactl[tid] = bact[tid];

    // W_mm fragments, register-resident. wave w: gate = w>>1 (0=m_a,1=m_c),
    // tile = w&1; col-tile ct = gate*64 + m*2 + tile; all 32 K-frags.
    bf16x8 wb[32];
    {
        int ct = (wave >> 1) * 64 + m * 2 + (wave & 1);
#pragma unroll
        for (int kb = 0; kb < 32; ++kb)
            wb[kb] = *(const bf16x8*)(pmm + (((size_t)ct * 32 + kb) * 64 + lane) * 8);
    }
    // W_im fragments: wave w in {0,1,2} = gate w; 2 col-tiles x 4 kb each
    bf16x8 wi[2][4];
    if (wave < 3) {
#pragma unroll
        for (int tl = 0; tl < 2; ++tl) {
            int ct2 = wave * 64 + m * 2 + tl;
#pragma unroll
            for (int kb2 = 0; kb2 < 4; ++kb2)
                wi[tl][kb2] = *(const bf16x8*)(pim + (((size_t)ct2 * 4 + kb2) * 64 + lane) * 8);
        }
    }
#pragma unroll
    for (int p = 0; p < 2; ++p) ownh[bloc][p * 16 + cl] = 0.f;

    struct I2 { f32x4 a0, a1; };
    auto comp_iacc = [&](int t) -> I2 {
        I2 r;
        r.a0 = (f32x4){0.f, 0.f, 0.f, 0.f};
        r.a1 = (f32x4){0.f, 0.f, 0.f, 0.f};
        if (wave < 3) {
#pragma unroll
            for (int kb2 = 0; kb2 < 4; ++kb2) {
                bf16x8 af = *(const bf16x8*)(inputs +
                    ((size_t)t * 64 + g * 16 + r16) * INSZ + kb2 * 32 + q * 8);
                r.a0 = __builtin_amdgcn_mfma_f32_16x16x32_bf16(af, wi[0][kb2], r.a0, 0, 0, 0);
                r.a1 = __builtin_amdgcn_mfma_f32_16x16x32_bf16(af, wi[1][kb2], r.a1, 0, 0, 0);
            }
        }
        return r;
    };

    // actor partial: thread covers 4 cols of Hlds[hrow]; wave-reduce; leaders -> aplds
    auto actor_emit = [&](int hrow) {
        float p0 = 0.f, p1 = 0.f, p2 = 0.f;
        int c0 = tid * 4;
        const bf16* hp = &Hlds[hrow][c0];
#pragma unroll
        for (int i = 0; i < 4; ++i) {
            float hv = (float)hp[i];
            p0 += hv * wact_lds[(c0 + i) * 3 + 0];
            p1 += hv * wact_lds[(c0 + i) * 3 + 1];
            p2 += hv * wact_lds[(c0 + i) * 3 + 2];
        }
#pragma unroll
        for (int off = 32; off >= 1; off >>= 1) {
            p0 += __shfl_xor(p0, off);
            p1 += __shfl_xor(p1, off);
            p2 += __shfl_xor(p2, off);
        }
        if (lane == 0) { aplds[wave][0] = p0; aplds[wave][1] = p1; aplds[wave][2] = p2; }
    };
    auto actor_fin = [&](int tout) {   // one thread; after a barrier following emit
        float l0 = aplds[0][0] + aplds[1][0] + aplds[2][0] + aplds[3][0] + bactl[0];
        float l1 = aplds[0][1] + aplds[1][1] + aplds[2][1] + aplds[3][1] + bactl[1];
        float l2 = aplds[0][2] + aplds[1][2] + aplds[2][2] + aplds[3][2] + bactl[2];
        float mx = fmaxf(l0, fmaxf(l1, l2));
        float e0 = __expf(l0 - mx), e1 = __expf(l1 - mx), e2 = __expf(l2 - mx);
        float inv = 1.f / (e0 + e1 + e2);
        float* o = out + ((size_t)(g * 16 + m) * L_SEQ + tout) * 3;
        __hip_atomic_store(o + 0, e0 * inv, __ATOMIC_RELAXED, __HIP_MEMORY_SCOPE_AGENT);
        __hip_atomic_store(o + 1, e1 * inv, __ATOMIC_RELAXED, __HIP_MEMORY_SCOPE_AGENT);
        __hip_atomic_store(o + 2, e2 * inv, __ATOMIC_RELAXED, __HIP_MEMORY_SCOPE_AGENT);
    };

    I2 iacc = comp_iacc(0);
    unsigned int* slots = ctr + g * 64;                    // 32 used per group
    unsigned int* epoch = ctr + NGROUP * 64 + g * 64;      // own cache line
    int spin_budget = 1 << 22;

#pragma clang loop unroll(disable)
    for (int t = 0; t < L_SEQ; ++t) {
        // every RING steps: drop stale cache lines before ring-slot reuse
        if (t != 0 && (t & (RING - 1)) == 0)
            __builtin_amdgcn_fence(__ATOMIC_ACQUIRE, "agent");

        // deposit this step's input-projection tiles
        if (wave < 3) {
#pragma unroll
            for (int reg = 0; reg < 4; ++reg) {
                ilds[t & 1][wave][0][q * 4 + reg][r16] = iacc.a0[reg];
                ilds[t & 1][wave][1][q * 4 + reg][r16] = iacc.a1[reg];
            }
        }
        // stage H^{t-1} from ring slot (t-1)&15: plain coalesced b128 loads
        {
            const bf16* src = hbuf +
                ((size_t)(((t + RING - 1) & (RING - 1)) * NGROUP + g)) * BG * MEM;
            bf16x8 tmp[8];
#pragma unroll
            for (int it = 0; it < 8; ++it) {
                int fi = it * 256 + tid;
                tmp[it] = *(const bf16x8*)(src + (size_t)(fi >> 7) * MEM + (fi & 127) * 8);
            }
#pragma unroll
            for (int it = 0; it < 8; ++it) {
                int fi = it * 256 + tid;
                *(bf16x8*)(&Hlds[fi >> 7][(fi & 127) * 8]) = tmp[it];
            }
        }
        __syncthreads();

        // m = H @ W_mm: wave owns one 16x16 col-tile over K=1024 (32 MFMAs)
        {
            f32x4 m0 = {0.f, 0.f, 0.f, 0.f};
            f32x4 m1 = {0.f, 0.f, 0.f, 0.f};
#pragma unroll
            for (int i = 0; i < 16; ++i) {
                bf16x8 a0 = *(const bf16x8*)(&Hlds[r16][(2 * i) * 32 + q * 8]);
                bf16x8 a1 = *(const bf16x8*)(&Hlds[r16][(2 * i + 1) * 32 + q * 8]);
                m0 = __builtin_amdgcn_mfma_f32_16x16x32_bf16(a0, wb[2 * i], m0, 0, 0, 0);
                m1 = __builtin_amdgcn_mfma_f32_16x16x32_bf16(a1, wb[2 * i + 1], m1, 0, 0, 0);
            }
#pragma unroll
            for (int reg = 0; reg < 4; ++reg)
                mlds[wave][q * 4 + reg][r16] = m0[reg] + m1[reg];
        }
        // actor partials for logits[t-1] of batch g*16+m (members m<16 only)
        if (m < 16 && t > 0) actor_emit(m);
        __syncthreads();

        // elementwise nBRC update: thread -> (batch bloc, cols cl and 16+cl)
        {
#pragma unroll
            for (int p = 0; p < 2; ++p) {
                float ma = mlds[p][bloc][cl];
                float mc = mlds[2 + p][bloc][cl];
                float ia = ilds[t & 1][0][p][bloc][cl];
                float ic = ilds[t & 1][1][p][bloc][cl];
                float io = ilds[t & 1][2][p][bloc][cl];
                float h0 = ownh[bloc][p * 16 + cl];
                float a = 1.f + fast_tanh(ia + ma);
                float c = fast_sigmoid(ic + mc);
                float hn = c * h0 + (1.f - c) * fast_tanh(io + a * h0);
                ownh[bloc][p * 16 + cl] = hn;
                hstage[bloc][p * 16 + cl] = (bf16)hn;
            }
        }
        __syncthreads();   // hstage complete; aplds complete

        // out stores on wave 1 so they don't sit in wave 0's publish drain
        if (m < 16 && t > 0 && tid == 64) actor_fin(t - 1);

        // publish H^t (1 KB = 128 ull): wave 0, write-through stores, drain, flag
        if (tid < 64) {
            bf16* base = hbuf + ((size_t)((t & (RING - 1)) * NGROUP + g)) * BG * MEM;
#pragma unroll
            for (int i = 0; i < 2; ++i) {
                int idx = i * 64 + lane;        // 0..127
                int row = idx >> 3, c = idx & 7;
                ull v = *(const ull*)(&hstage[row][c * 4]);
                ull* dst = (ull*)(base + (size_t)row * MEM + m * 32) + c;
                __hip_atomic_store(dst, v, __ATOMIC_RELAXED, __HIP_MEMORY_SCOPE_AGENT);
            }
            asm volatile("s_waitcnt vmcnt(0)" ::: "memory");   // acked at MALL
            if (lane == 0)
                __hip_atomic_store(&slots[m], (unsigned)(t + 1), __ATOMIC_RELAXED,
                                   __HIP_MEMORY_SCOPE_AGENT);
        }

        // waves 0-2 prefetch next i-proj; wave 3 runs the hierarchical barrier
        if (t + 1 < L_SEQ) iacc = comp_iacc(t + 1);
        {
            unsigned target = (unsigned)(t + 1);
            if (wave == 3) {
                if (m == 0) {
                    // aggregator: lanes<32 poll the 32 slots; then publish epoch
                    bool done = false;
                    while (!done && --spin_budget > 0) {
                        unsigned v = target;
                        if (lane < 32)
                            v = __hip_atomic_load(&slots[lane], __ATOMIC_RELAXED,
                                                  __HIP_MEMORY_SCOPE_AGENT);
                        done = (bool)__all((int)(v >= target));
                        if (!done) __builtin_amdgcn_s_sleep(1);
                    }
                    if (lane == 0)
                        __hip_atomic_store(epoch, target, __ATOMIC_RELAXED,
                                           __HIP_MEMORY_SCOPE_AGENT);
                } else {
                    // consumers: lane 0 polls the single epoch word
                    unsigned e = 0;
                    while (e < target && --spin_budget > 0) {
                        unsigned v = 0;
                        if (lane == 0)
                            v = __hip_atomic_load(epoch, __ATOMIC_RELAXED,
                                                  __HIP_MEMORY_SCOPE_AGENT);
                        e = __builtin_amdgcn_readfirstlane(v);
                        if (e < target) __builtin_amdgcn_s_sleep(1);
                    }
                }
            }
        }
        __syncthreads();
    }

    // epilogue: logits/softmax for t = L-1 from ring slot 15 (fresh read needed)
    if (m < 16) {
        __builtin_amdgcn_fence(__ATOMIC_ACQUIRE, "agent");
        const bf16* src = hbuf + ((size_t)(((L_SEQ - 1) & (RING - 1)) * NGROUP + g)) * BG * MEM +
                          (size_t)m * MEM;
        *(ull*)(&Hlds[0][tid * 4]) = *(const ull*)(src + tid * 4);
        __syncthreads();
        actor_emit(0);
        __syncthreads();
        if (tid == 0) actor_fin(L_SEQ - 1);
    }
}

extern "C" void kernel_launch(void* const* d_in, const int* in_sizes, int n_in,
                              void* d_out, int out_size, void* d_ws, size_t ws_size,
                              hipStream_t stream) {
    const float* x    = (const float*)d_in[0];
    const float* Ws   = (const float*)d_in[1];
    const float* bs   = (const float*)d_in[2];
    const float* Wim  = (const float*)d_in[3];
    const float* Wmm  = (const float*)d_in[4];
    const float* Wact = (const float*)d_in[5];
    const float* bact = (const float*)d_in[6];

    char* ws = (char*)d_ws;
    bf16* inputs = (bf16*)(ws + OFF_INPUTS);
    bf16* pmm    = (bf16*)(ws + OFF_WMM);
    bf16* pim    = (bf16*)(ws + OFF_WIM);
    bf16* hbuf   = (bf16*)(ws + OFF_HBUF);
    unsigned int* ctr = (unsigned int*)(ws + OFF_CTR);

    hipMemsetAsync(hbuf, 0, SZ_HBUF, stream);   // slot 15 zeros = H^{-1}
    hipMemsetAsync(ctr, 0, SZ_CTR, stream);

    k_sense<<<L_SEQ, 256, 0, stream>>>(x, Ws, bs, inputs);
    k_pack<<<(128 * 32 * 64 * 8 + 192 * 4 * 64 * 8) / 256, 256, 0, stream>>>(Wmm, Wim, pmm, pim);
    k_main<<<NGROUP * NMEM, 256, 0, stream>>>(inputs, pmm, pim, Wact, bact, hbuf,
                                              (float*)d_out, ctr);
}